// Round 11
// baseline (398.162 us; speedup 1.0000x reference)
//
#include <hip/hip_runtime.h>
#include <hip/hip_bf16.h>

typedef short bf16x8 __attribute__((ext_vector_type(8)));
typedef float f32x4 __attribute__((ext_vector_type(4)));

static inline int cdiv(int a, int b){ return (a + b - 1) / b; }

__device__ __forceinline__ unsigned pack_bf16_hi(float v){
    return ((unsigned)__bfloat16_as_ushort(__float2bfloat16(v))) << 16;
}
__device__ __forceinline__ float bf16hi_to_f32(unsigned bits_hi16){
    return __uint_as_float(bits_hi16);  // bf16 bits already in [31:16]
}

// ---------- direct CSR build: per-target histogram (global atomics, L2) ----------
__global__ __launch_bounds__(256) void k_hist(const int* __restrict__ tgt,
                                              int* __restrict__ cnt, int E){
    int stride = gridDim.x * 256;
    for (int e = blockIdx.x * 256 + threadIdx.x; e < E; e += stride)
        atomicAdd(&cnt[tgt[e]], 1);
}

// ---------- scan: cnt[N] -> rs exclusive prefix (3 tiny kernels) ----------
__global__ __launch_bounds__(256) void k_scanA(const int* __restrict__ cnt,
                                               int* __restrict__ rs,
                                               int* __restrict__ part, int N){
    __shared__ int sc[256];
    int tid = threadIdx.x;
    int base = blockIdx.x * 1024 + tid * 4;
    int v0 = (base + 0 < N) ? cnt[base + 0] : 0;
    int v1 = (base + 1 < N) ? cnt[base + 1] : 0;
    int v2 = (base + 2 < N) ? cnt[base + 2] : 0;
    int v3 = (base + 3 < N) ? cnt[base + 3] : 0;
    int t3 = v0 + v1 + v2 + v3;
    sc[tid] = t3;
    __syncthreads();
    for (int off = 1; off < 256; off <<= 1){
        int x = (tid >= off) ? sc[tid - off] : 0;
        __syncthreads();
        sc[tid] += x;
        __syncthreads();
    }
    int ex = sc[tid] - t3;
    if (base + 0 < N) rs[base + 0] = ex;
    if (base + 1 < N) rs[base + 1] = ex + v0;
    if (base + 2 < N) rs[base + 2] = ex + v0 + v1;
    if (base + 3 < N) rs[base + 3] = ex + v0 + v1 + v2;
    if (tid == 255) part[blockIdx.x] = sc[255];
}

__global__ void k_scanB(int* __restrict__ part, int nb){
    if (blockIdx.x == 0 && threadIdx.x == 0){
        int acc = 0;
        for (int i = 0; i < nb; ++i){ int t = part[i]; part[i] = acc; acc += t; }
    }
}

__global__ __launch_bounds__(256) void k_scanC(int* __restrict__ rs,
                                               int* __restrict__ cur,
                                               const int* __restrict__ part,
                                               int N, int E){
    int i = blockIdx.x * 1024 + threadIdx.x * 4;
    int b = part[blockIdx.x];
    #pragma unroll
    for (int u = 0; u < 4; ++u){
        int j = i + u;
        if (j < N){ int v = rs[j] + b; rs[j] = v; cur[j] = v; }
    }
    if (blockIdx.x == 0 && threadIdx.x == 0) rs[N] = E;
}

// ---------- scatter: edge payload straight to its CSR slot (8B writes) ----------
// Replaces bcnt0+bscan+bin+bucket: no binned round-trip (32MB saved), half-size
// scatter payload. Order within a target's segment is arbitrary (sum-invariant).
__global__ __launch_bounds__(256) void k_scatter(
        const int* __restrict__ src, const int* __restrict__ tgt,
        const float* __restrict__ asp, const float* __restrict__ actx,
        const float* __restrict__ alat, const float* __restrict__ wsp,
        const float* __restrict__ wctx, const float* __restrict__ wlat,
        int* __restrict__ cur, uint2* __restrict__ effo, int E){
    int stride = gridDim.x * 256;
    for (int e = blockIdx.x * 256 + threadIdx.x; e < E; e += stride){
        int t = tgt[e];
        int p = atomicAdd(&cur[t], 1);
        uint2 o;
        o.x = (unsigned)src[e] | pack_bf16_hi(asp[e] * wsp[e]);
        o.y = (pack_bf16_hi(actx[e] * wctx[e]) >> 16) | pack_bf16_hi(alat[e] * wlat[e]);
        effo[p] = o;
    }
}

// ---------- deg: thread-per-node segment sum -> dinv for all layers (round-0) ----
__global__ __launch_bounds__(256) void k_deg(
        const uint2* __restrict__ effo, const int* __restrict__ rs,
        const float* __restrict__ dp,        // [L*3]
        float* __restrict__ dinv_all,        // [L][N][3]
        int N, int L){
    int n = blockIdx.x * 256 + threadIdx.x;
    if (n >= N) return;
    int beg = rs[n], end = rs[n + 1];
    float s0 = 0.f, s1 = 0.f, s2 = 0.f;
    for (int i = beg; i < end; ++i){
        uint2 v = effo[i];
        s0 += bf16hi_to_f32(v.x & 0xFFFF0000u);
        s1 += bf16hi_to_f32(v.y << 16);
        s2 += bf16hi_to_f32(v.y & 0xFFFF0000u);
    }
    float d0 = fmaxf(1.f + s0, 1e-6f);
    float d1 = fmaxf(1.f + s1, 1e-6f);
    float d2 = fmaxf(1.f + s2, 1e-6f);
    for (int l = 0; l < L; ++l){
        size_t base = ((size_t)l * N + n) * 3;
        dinv_all[base + 0] = powf(d0, dp[l * 3 + 0]);
        dinv_all[base + 1] = powf(d1, dp[l * 3 + 1]);
        dinv_all[base + 2] = powf(d2, dp[l * 3 + 2]);
    }
}

// -------- merged prep: nv (all layers) + xg convert (float4) + BT concat -------
__global__ void k_prep(const uint2* __restrict__ effo,
                       const float* __restrict__ dinv_all,  // [L][N][3]
                       uint2* __restrict__ nv,
                       const float* __restrict__ x, __hip_bfloat16* __restrict__ xg,
                       const float* __restrict__ Wself, const float* __restrict__ W3,
                       __hip_bfloat16* __restrict__ BT,
                       int N, int E, int L){
    int gid = blockIdx.x * 256 + threadIdx.x;
    int LE = L * E;
    int nx4 = (N * 128) >> 2;
    int nw = L * 65536;
    if (gid < LE){
        int l = gid / E;
        int e = gid - l * E;
        const float* dinv = dinv_all + (size_t)l * N * 3;
        uint2 v = effo[e];
        unsigned s = v.x & 0xFFFFu;
        float e0 = bf16hi_to_f32(v.x & 0xFFFF0000u);
        float e1 = bf16hi_to_f32(v.y << 16);
        float e2 = bf16hi_to_f32(v.y & 0xFFFF0000u);
        uint2 o;
        o.x = s | pack_bf16_hi(e0 * dinv[3 * s + 0]);
        o.y = (pack_bf16_hi(e1 * dinv[3 * s + 1]) >> 16)
            | pack_bf16_hi(e2 * dinv[3 * s + 2]);
        nv[gid] = o;
    } else if (gid < LE + nx4){
        int i = gid - LE;
        float4 v = ((const float4*)x)[i];
        float2 lo = {v.x, v.y}, hi = {v.z, v.w};
        ((__hip_bfloat162*)xg)[2 * i]     = __float22bfloat162_rn(lo);
        ((__hip_bfloat162*)xg)[2 * i + 1] = __float22bfloat162_rn(hi);
    } else if (gid < LE + nx4 + nw){
        int q = gid - LE - nx4;
        int l = q >> 16, r = q & 65535;
        int j = r >> 9, k = r & 511;
        float v;
        if (k < 128) v = Wself[l * 16384 + k * 128 + j];
        else {
            int c = (k >> 7) - 1, kk = k & 127;
            v = W3[l * 49152 + (c * 128 + kk) * 128 + j];
        }
        BT[q] = __float2bfloat16(v);
    }
}

// ---------------- aggregate: Y_c[t] = dt_c * sum_e nv_c[e] * x[src[e]] ----------
// round-0 proven structure — AT ITS FLOOR (48.2us, 100.6MB compulsory, 2.9TB/s).
__global__ __launch_bounds__(256) void k_msg(
        const __hip_bfloat16* __restrict__ xg,  // [N][128] bf16 compact
        __hip_bfloat16* __restrict__ Yg,        // [N][384] bf16 compact (out)
        const uint2* __restrict__ nv,           // [E] packed, CSR order (this layer)
        const int* __restrict__ rs,             // [N+1]
        const float* __restrict__ dinv,         // [N][3] (this layer)
        int N){
    int w = threadIdx.x >> 6, lane = threadIdx.x & 63;
    int t = blockIdx.x * 4 + w;
    if (t >= N) return;
    float ax0 = 0.f, ay0 = 0.f, ax1 = 0.f, ay1 = 0.f, ax2 = 0.f, ay2 = 0.f;
    int beg = rs[t], end = rs[t + 1];
    int i = beg;
    for (; i + 8 <= end; i += 8){
        uint2 m[8];
        #pragma unroll
        for (int u = 0; u < 8; ++u) m[u] = nv[i + u];
        float2 f[8];
        #pragma unroll
        for (int u = 0; u < 8; ++u){
            const __hip_bfloat162* p =
                (const __hip_bfloat162*)(xg + (size_t)(m[u].x & 0xFFFFu) * 128);
            f[u] = __bfloat1622float2(p[lane]);
        }
        #pragma unroll
        for (int u = 0; u < 8; ++u){
            float n0 = bf16hi_to_f32(m[u].x & 0xFFFF0000u);
            float n1 = bf16hi_to_f32(m[u].y << 16);
            float n2 = bf16hi_to_f32(m[u].y & 0xFFFF0000u);
            ax0 += n0 * f[u].x; ay0 += n0 * f[u].y;
            ax1 += n1 * f[u].x; ay1 += n1 * f[u].y;
            ax2 += n2 * f[u].x; ay2 += n2 * f[u].y;
        }
    }
    for (; i < end; ++i){
        uint2 m = nv[i];
        const __hip_bfloat162* p =
            (const __hip_bfloat162*)(xg + (size_t)(m.x & 0xFFFFu) * 128);
        float2 fv = __bfloat1622float2(p[lane]);
        float n0 = bf16hi_to_f32(m.x & 0xFFFF0000u);
        float n1 = bf16hi_to_f32(m.y << 16);
        float n2 = bf16hi_to_f32(m.y & 0xFFFF0000u);
        ax0 += n0 * fv.x; ay0 += n0 * fv.y;
        ax1 += n1 * fv.x; ay1 += n1 * fv.y;
        ax2 += n2 * fv.x; ay2 += n2 * fv.y;
    }
    float dt0 = dinv[3 * t], dt1 = dinv[3 * t + 1], dt2 = dinv[3 * t + 2];
    __hip_bfloat162* yo = (__hip_bfloat162*)(Yg + (size_t)t * 384) + lane;
    float2 r0 = {dt0 * ax0, dt0 * ay0};
    float2 r1 = {dt1 * ax1, dt1 * ay1};
    float2 r2 = {dt2 * ax2, dt2 * ay2};
    yo[0]   = __float22bfloat162_rn(r0);
    yo[64]  = __float22bfloat162_rn(r1);
    yo[128] = __float22bfloat162_rn(r2);
}

// ---------------- GEMM: out = [xg|Yg][M,512] @ B[512,128] + bias; opt fused LN+ReLU
__global__ __launch_bounds__(256) void k_gemm(
        const __hip_bfloat16* __restrict__ Yg,  // [M,384] bf16
        const __hip_bfloat16* __restrict__ BT,  // [128,512] bf16 ([j][k])
        const float* __restrict__ bias,         // [128] fp32
        float* __restrict__ outbuf,             // [M,128] (doLN==0)
        int M, int doLN,
        const float* __restrict__ g, const float* __restrict__ b,
        __hip_bfloat16* __restrict__ xg){       // [M,128]: A kt=0 source; LN target
    __shared__ __hip_bfloat16 As[64 * 128];     // 16KB
    __shared__ __hip_bfloat16 Bs[128 * 128];    // 32KB
    const int tid = threadIdx.x;
    const int row0 = blockIdx.x * 64;
    const int w = tid >> 6, lane = tid & 63;
    const int wm = (w & 1) * 32, wn = (w >> 1) * 64;
    const int lm = lane & 15, lq = lane >> 4;

    f32x4 acc[2][4];
    #pragma unroll
    for (int mt = 0; mt < 2; ++mt)
        #pragma unroll
        for (int nt = 0; nt < 4; ++nt)
            acc[mt][nt] = {0.f, 0.f, 0.f, 0.f};

    for (int kt = 0; kt < 4; ++kt){
        #pragma unroll
        for (int it = 0; it < 4; ++it){
            int v = it * 256 + tid;
            int r = v >> 4, c = v & 15;
            int soff = r * 128 + ((c ^ (r & 15)) << 3);
            int4 av = {0, 0, 0, 0};
            if (row0 + r < M){
                if (kt == 0)
                    av = *(const int4*)(xg + (size_t)(row0 + r) * 128 + (c << 3));
                else
                    av = *(const int4*)(Yg + (size_t)(row0 + r) * 384
                                        + (kt - 1) * 128 + (c << 3));
            }
            *(int4*)(&As[soff]) = av;
        }
        #pragma unroll
        for (int it = 0; it < 8; ++it){
            int v = it * 256 + tid;
            int r = v >> 4, c = v & 15;
            int soff = r * 128 + ((c ^ (r & 15)) << 3);
            int4 bv = *(const int4*)(BT + (size_t)r * 512 + kt * 128 + (c << 3));
            *(int4*)(&Bs[soff]) = bv;
        }
        __syncthreads();

        #pragma unroll
        for (int kk = 0; kk < 4; ++kk){
            int kc = kk * 4 + lq;
            bf16x8 a[2], b2[4];
            #pragma unroll
            for (int mt = 0; mt < 2; ++mt){
                int r = wm + mt * 16 + lm;
                a[mt] = *(const bf16x8*)(&As[r * 128 + ((kc ^ (r & 15)) << 3)]);
            }
            #pragma unroll
            for (int nt = 0; nt < 4; ++nt){
                int r = wn + nt * 16 + lm;
                b2[nt] = *(const bf16x8*)(&Bs[r * 128 + ((kc ^ (r & 15)) << 3)]);
            }
            #pragma unroll
            for (int mt = 0; mt < 2; ++mt)
                #pragma unroll
                for (int nt = 0; nt < 4; ++nt)
                    acc[mt][nt] = __builtin_amdgcn_mfma_f32_16x16x32_bf16(
                        a[mt], b2[nt], acc[mt][nt], 0, 0, 0);
        }
        __syncthreads();
    }

    if (!doLN){
        #pragma unroll
        for (int mt = 0; mt < 2; ++mt){
            #pragma unroll
            for (int nt = 0; nt < 4; ++nt){
                int col = wn + nt * 16 + lm;
                #pragma unroll
                for (int r = 0; r < 4; ++r){
                    int row = row0 + wm + mt * 16 + lq * 4 + r;
                    if (row < M)
                        outbuf[(size_t)row * 128 + col] = acc[mt][nt][r] + bias[col];
                }
            }
        }
    } else {
        float* S1 = (float*)As;          // [64][32] sum partials
        float* S2 = S1 + 2048;           // [64][32] sumsq partials
        float* MS = (float*)Bs;          // mu[64], sc[64]
        const int half = wn >> 6;        // 0 or 1
        const int slot = half * 16 + lm;
        float bv[4];
        #pragma unroll
        for (int nt = 0; nt < 4; ++nt) bv[nt] = bias[wn + nt * 16 + lm];
        #pragma unroll
        for (int mt = 0; mt < 2; ++mt){
            #pragma unroll
            for (int r = 0; r < 4; ++r){
                int rl = wm + mt * 16 + lq * 4 + r;
                float ps = 0.f, pq = 0.f;
                #pragma unroll
                for (int nt = 0; nt < 4; ++nt){
                    float v = acc[mt][nt][r] + bv[nt];
                    ps += v; pq += v * v;
                }
                S1[rl * 32 + slot] = ps;
                S2[rl * 32 + slot] = pq;
            }
        }
        __syncthreads();
        if (tid < 64){
            float s = 0.f, sq = 0.f;
            #pragma unroll
            for (int j = 0; j < 32; ++j){
                s  += S1[tid * 32 + j];
                sq += S2[tid * 32 + j];
            }
            float mu = s * (1.0f / 128.0f);
            float var = sq * (1.0f / 128.0f) - mu * mu;
            MS[tid] = mu;
            MS[64 + tid] = rsqrtf(var + 1e-5f);
        }
        __syncthreads();
        float gv[4], bbv[4];
        #pragma unroll
        for (int nt = 0; nt < 4; ++nt){
            int col = wn + nt * 16 + lm;
            gv[nt] = g[col]; bbv[nt] = b[col];
        }
        #pragma unroll
        for (int mt = 0; mt < 2; ++mt){
            #pragma unroll
            for (int r = 0; r < 4; ++r){
                int rl = wm + mt * 16 + lq * 4 + r;
                int row = row0 + rl;
                if (row < M){
                    float mu = MS[rl], sc = MS[64 + rl];
                    #pragma unroll
                    for (int nt = 0; nt < 4; ++nt){
                        int col = wn + nt * 16 + lm;
                        float v = acc[mt][nt][r] + bv[nt];
                        float y = fmaxf((v - mu) * sc * gv[nt] + bbv[nt], 0.0f);
                        xg[(size_t)row * 128 + col] = __float2bfloat16(y);
                    }
                }
            }
        }
    }
}

extern "C" void kernel_launch(void* const* d_in, const int* in_sizes, int n_in,
                              void* d_out, int out_size, void* d_ws, size_t ws_size,
                              hipStream_t stream) {
    const float* x     = (const float*)d_in[0];
    const int*   ei    = (const int*)d_in[1];
    const float* asp   = (const float*)d_in[2];
    const float* actx  = (const float*)d_in[3];
    const float* alat  = (const float*)d_in[4];
    const float* wsp   = (const float*)d_in[5];
    const float* wctx  = (const float*)d_in[6];
    const float* wlat  = (const float*)d_in[7];
    const float* W3    = (const float*)d_in[8];
    const float* Wself = (const float*)d_in[9];
    const float* bias  = (const float*)d_in[10];
    const float* dpow  = (const float*)d_in[11];
    const float* lng   = (const float*)d_in[12];
    const float* lnb   = (const float*)d_in[13];

    const int N = in_sizes[0] / 128;
    const int E = in_sizes[1] / 2;
    const int L = in_sizes[8] / (3 * 128 * 128);
    const int* src = ei;
    const int* tgt = ei + E;

    // workspace carve (256B-aligned); footprint ~= proven ~77MB layout
    char* p = (char*)d_ws;
    auto alloc = [&](size_t bytes) -> void* {
        void* r = (void*)p;
        p += (bytes + 255) & ~(size_t)255;
        return r;
    };
    int*   rs       = (int*)  alloc((size_t)(N + 1) * 4);
    int*   cnt      = (int*)  alloc((size_t)N * 4);
    int*   cur      = (int*)  alloc((size_t)N * 4);
    int*   part     = (int*)  alloc(256 * 4);
    uint2* effo     = (uint2*)alloc((size_t)E * 8);
    uint2* nv       = (uint2*)alloc((size_t)L * E * 8);
    float* dinv_all = (float*)alloc((size_t)L * N * 3 * 4);   // [L][N][3]
    __hip_bfloat16* xg = (__hip_bfloat16*)alloc((size_t)N * 128 * 2);  // [N][128]
    __hip_bfloat16* Yg = (__hip_bfloat16*)alloc((size_t)N * 384 * 2);  // [N][384]
    __hip_bfloat16* BT = (__hip_bfloat16*)alloc((size_t)L * 128 * 512 * 2);

    const int nb = cdiv(N, 1024);

    // ---- prep: direct CSR build (global-atomic hist -> scan -> scatter) ----
    hipMemsetAsync(cnt, 0, (size_t)N * 4, stream);
    k_hist   <<<2048, 256, 0, stream>>>(tgt, cnt, E);
    k_scanA  <<<nb, 256, 0, stream>>>(cnt, rs, part, N);
    k_scanB  <<<1, 64, 0, stream>>>(part, nb);
    k_scanC  <<<nb, 256, 0, stream>>>(rs, cur, part, N, E);
    k_scatter<<<2048, 256, 0, stream>>>(src, tgt, asp, actx, alat, wsp, wctx, wlat,
                                        cur, effo, E);
    k_deg    <<<cdiv(N, 256), 256, 0, stream>>>(effo, rs, dpow, dinv_all, N, L);
    {
        int total = L * E + ((N * 128) >> 2) + L * 65536;
        k_prep<<<cdiv(total, 256), 256, 0, stream>>>(effo, dinv_all, nv, x, xg,
                                                     Wself, W3, BT, N, E, L);
    }

    // ---- layers ----
    for (int l = 0; l < L; ++l){
        int doLN = (l < L - 1) ? 1 : 0;
        const float* dinv_l = dinv_all + (size_t)l * N * 3;
        k_msg <<<cdiv(N, 4), 256, 0, stream>>>(xg, Yg, nv + (size_t)l * E, rs, dinv_l, N);
        k_gemm<<<cdiv(N, 64), 256, 0, stream>>>(Yg, BT + (size_t)l * 65536,
                                                bias + l * 128, (float*)d_out, N,
                                                doLN, lng, lnb, xg);
    }
}